// Round 10
// baseline (121.088 us; speedup 1.0000x reference)
//
#include <hip/hip_runtime.h>
#include <hip/hip_bf16.h>
#include <stdint.h>

// Problem constants (B=4, T=2048, C=512, H=8, D=64)
constexpr int Bn = 4;
constexpr int Tn = 2048;
constexpr int Cn = 512;
constexpr int Hn = 8;
constexpr int Dn = 64;
constexpr int BT = Bn * Tn;          // 8192
constexpr int NQKV = 3 * Cn;         // 1536

typedef __attribute__((ext_vector_type(4))) float  f32x4;
typedef __attribute__((ext_vector_type(8))) short  s16x8;
typedef __attribute__((ext_vector_type(4))) short  s16x4;

__device__ __forceinline__ short f2bs(float f) {
    __hip_bfloat16 h = __float2bfloat16(f);
    return *reinterpret_cast<short*>(&h);
}

// async global->LDS, 16B per lane (linear LDS dest: wave base + lane*16)
__device__ __forceinline__ void gload16(const short* g, short* l) {
    __builtin_amdgcn_global_load_lds(
        (const __attribute__((address_space(1))) void*)g,
        (__attribute__((address_space(3))) void*)l, 16, 0, 0);
}

// ---------------- conversion / setup kernels ----------------

__global__ __launch_bounds__(256) void k_conv_x(const float* __restrict__ x,
                                                short* __restrict__ xb) {
    int i = blockIdx.x * 256 + threadIdx.x;          // one float4 per thread
    f32x4 v = reinterpret_cast<const f32x4*>(x)[i];
    s16x4 o;
    o[0] = f2bs(v[0]); o[1] = f2bs(v[1]); o[2] = f2bs(v[2]); o[3] = f2bs(v[3]);
    reinterpret_cast<s16x4*>(xb)[i] = o;
}

// Coalesced weight transpose+convert via 64x64 LDS tile (both weights, 1 dispatch).
__global__ __launch_bounds__(256) void k_wTt(const float* __restrict__ Wqkv,
                                             const float* __restrict__ Wproj,
                                             short* __restrict__ wqkvT,
                                             short* __restrict__ wprojT) {
    int bid = blockIdx.x;
    const float* W; short* out; int N, n0, k0;
    if (bid < 192) {                  // 1536/64 * 512/64 = 24*8
        W = Wqkv; out = wqkvT; N = NQKV;
        n0 = (bid >> 3) * 64; k0 = (bid & 7) * 64;
    } else {
        bid -= 192;                   // 512/64 * 512/64 = 8*8
        W = Wproj; out = wprojT; N = Cn;
        n0 = (bid >> 3) * 64; k0 = (bid & 7) * 64;
    }
    __shared__ float lds[64 * 65];
    const int tid = threadIdx.x;
#pragma unroll
    for (int i = 0; i < 16; ++i) {
        int flat = i * 256 + tid;
        int k = flat >> 6, n = flat & 63;
        lds[n * 65 + k] = W[(size_t)(k0 + k) * N + n0 + n];
    }
    __syncthreads();
#pragma unroll
    for (int i = 0; i < 16; ++i) {
        int flat = i * 256 + tid;
        int n = flat >> 6, k = flat & 63;
        out[(size_t)(n0 + n) * 512 + k0 + k] = f2bs(lds[n * 65 + k]);
    }
}

// packed cos/sin table: csT[t*64+d] = (cos, sin)
__global__ __launch_bounds__(256) void k_rope(float2* __restrict__ csT) {
    int i = blockIdx.x * 256 + threadIdx.x;          // < T*D
    int t = i >> 6, d = i & 63;
    float inv = exp2f(-(float)(d & 31) * 0.41524101186f);
    float fr = (float)t * inv;
    csT[i] = make_float2(cosf(fr), sinf(fr));
}

// ---------------- GEMM (128x128 tile, BK=64, double-buffered LDS) -------------
// (unchanged from round 9 — staging hides under the 32-MFMA compute phase)

template <int MODE>
__global__ __launch_bounds__(256, 2) void gemm_kernel(
    const short* __restrict__ A, const short* __restrict__ Bt,
    const float2* __restrict__ csT,
    short* __restrict__ Qb, short* __restrict__ Kb, short* __restrict__ Vt,
    float* __restrict__ outF) {
    const int m0 = blockIdx.y * 128;
    const int n0 = blockIdx.x * 128;
    const int tid = threadIdx.x;
    const int w = tid >> 6, lane = tid & 63;
    const int qi = lane & 15, g = lane >> 4;
    const int wr = w >> 1, wc = w & 1;

    __shared__ short As[2][128 * 64];
    __shared__ short Bs[2][128 * 64];

    f32x4 acc[4][4];
#pragma unroll
    for (int mt = 0; mt < 4; ++mt)
#pragma unroll
        for (int nt = 0; nt < 4; ++nt) acc[mt][nt] = (f32x4){0.f, 0.f, 0.f, 0.f};

    const int lr = lane >> 3;           // sub-row within 8-row slot
    const int lc = (lane & 7) ^ lr;     // pre-swizzled global chunk

#define STAGEG(buf, k0)                                                         \
    {                                                                           \
        _Pragma("unroll")                                                       \
        for (int s4_ = 0; s4_ < 4; ++s4_) {                                     \
            int slot_ = s4_ * 4 + w;                                            \
            int r_ = slot_ * 8 + lr;                                            \
            gload16(&A[(size_t)(m0 + r_) * 512 + (k0) + lc * 8],                \
                    &As[buf][slot_ * 512 + lane * 8]);                          \
            gload16(&Bt[(size_t)(n0 + r_) * 512 + (k0) + lc * 8],               \
                    &Bs[buf][slot_ * 512 + lane * 8]);                          \
        }                                                                       \
    }

    STAGEG(0, 0);
    __syncthreads();

    for (int it = 0; it < 8; ++it) {                 // K = 8 * 64
        if (it + 1 < 8) STAGEG((it + 1) & 1, (it + 1) * 64);
        const int cur = it & 1;
#pragma unroll
        for (int kk = 0; kk < 2; ++kk) {
            s16x8 af[4], bf[4];
#pragma unroll
            for (int mt = 0; mt < 4; ++mt) {
                int row = wr * 64 + mt * 16 + qi;
                af[mt] = *(const s16x8*)&As[cur][row * 64 + (((kk << 2) | g) ^ (qi & 7)) * 8];
            }
#pragma unroll
            for (int nt = 0; nt < 4; ++nt) {
                int row = wc * 64 + nt * 16 + qi;
                bf[nt] = *(const s16x8*)&Bs[cur][row * 64 + (((kk << 2) | g) ^ (qi & 7)) * 8];
            }
#pragma unroll
            for (int mt = 0; mt < 4; ++mt)
#pragma unroll
                for (int nt = 0; nt < 4; ++nt)
                    acc[mt][nt] = __builtin_amdgcn_mfma_f32_16x16x32_bf16(
                        af[mt], bf[nt], acc[mt][nt], 0, 0, 0);
        }
        __syncthreads();
    }
#undef STAGEG

    if (MODE == 1) {
#pragma unroll
        for (int mt = 0; mt < 4; ++mt)
#pragma unroll
            for (int nt = 0; nt < 4; ++nt)
#pragma unroll
                for (int r = 0; r < 4; ++r)
                    outF[(size_t)(m0 + wr * 64 + mt * 16 + 4 * g + r) * 512 +
                         n0 + wc * 64 + nt * 16 + qi] = acc[mt][nt][r];
    } else {
        const int seg64 = (n0 >> 6) + wc;            // = h*3 + seg
        const int h = seg64 / 3;
        const int seg = seg64 % 3;                   // 0=q 1=k 2=v
        const int b = m0 >> 11;
        const int tb = (m0 & 2047) + wr * 64;
        const float QSC = 0.125f * 1.44269504f;      // pre-fold softmax scale into Q
        if (seg == 2) {
            // V transposed + fragment-permuted: Vt[bh][d][ (t&~31) + g2*8 + sub2*4 + r2 ]
            const size_t vbase = (size_t)(b * Hn + h) * Dn;
#pragma unroll
            for (int mt = 0; mt < 4; ++mt)
#pragma unroll
                for (int nt = 0; nt < 4; ++nt)
#pragma unroll
                    for (int r = 0; r < 4; ++r) {
                        int t = tb + mt * 16 + 4 * g + r;
                        int d = nt * 16 + qi;
                        int o = t & 31;
                        int jj = (t & ~31) + ((o >> 2) & 3) * 8 + (o >> 4) * 4 + (o & 3);
                        Vt[(vbase + d) * Tn + jj] = f2bs(acc[mt][nt][r]);
                    }
        } else {
            short* dst = (seg == 0) ? Qb : Kb;
            const float post = (seg == 0) ? QSC : 1.0f;
            const size_t headbase = (size_t)(b * Hn + h) * Tn;
#pragma unroll
            for (int mt = 0; mt < 4; ++mt)
#pragma unroll
                for (int nt = 0; nt < 4; ++nt)
#pragma unroll
                    for (int r = 0; r < 4; ++r) {
                        int t = tb + mt * 16 + 4 * g + r;
                        int d = nt * 16 + qi;
                        float val = acc[mt][nt][r];
                        float pv = (nt < 2) ? -acc[mt][nt + 2][r] : acc[mt][nt - 2][r];
                        float2 cs = csT[t * 64 + d];
                        dst[(headbase + t) * Dn + d] = f2bs((val * cs.x + pv * cs.y) * post);
                    }
        }
    }
}

// ---------------- causal flash attention (parity split-K, 32 q-rows/wave) ------
// Block = 4 waves (256 thr), 64 q-rows of one bh. Wave w: row-half p=w&1 (rows
// q0+p*32..+31), chunk-parity par=w>>1 (computes chunks with ch&1==par).
// K/V fragment reads are SHARED across a wave's 2 qs-subtiles -> LDS read
// traffic per chunk-visit = 2 waves x 16KB = 32KB (HALF of round 8's 64KB);
// LDS-BW floor ~10.5us/CU. All 4 waves stage every chunk (dbuf, stage-ahead).
// Grid 1024 blocks (32 qt x 32 bh), heavy-first, bh in low bits; 32KB LDS ->
// ~4 blocks/CU with backfill. FIXED-BASE softmax => partials merge by plain
// SUM: waves 2,3 write O/l partials to LDS scratch, waves 0,1 add+normalize.

__global__ __launch_bounds__(256, 4) void attn_kernel(const short* __restrict__ Qb,
                                                      const short* __restrict__ Kb,
                                                      const short* __restrict__ Vt,
                                                      short* __restrict__ AO) {
    const int idx = blockIdx.x;
    const int bh = idx & 31;
    const int qt = 31 - (idx >> 5);                  // heavy tiles dispatch first
    const int q0 = qt * 64;
    const int tid = threadIdx.x;
    const int w = tid >> 6, lane = tid & 63;
    const int qi = lane & 15, g = lane >> 4;
    const int p = w & 1;                             // row-half
    const int par = w >> 1;                          // chunk parity
    const int b = bh >> 3, h = bh & 7;

    __shared__ short Ks[2][64 * 64];     // [key][d], chunk-swizzled
    __shared__ short Vs[2][64 * 64];     // [d][key-perm], chunk-swizzled

    const short* Qh = Qb + (size_t)bh * Tn * Dn;
    const short* Kh = Kb + (size_t)bh * Tn * Dn;
    const short* Vh = Vt + (size_t)bh * Dn * Tn;

    const int wrow0 = q0 + p * 32;       // wave's 32 query rows
    s16x8 qf[2][2];
#pragma unroll
    for (int qs = 0; qs < 2; ++qs)
#pragma unroll
        for (int dh = 0; dh < 2; ++dh)
            qf[qs][dh] = *(const s16x8*)&Qh[(size_t)(wrow0 + qs * 16 + qi) * Dn +
                                            dh * 32 + g * 8];

    f32x4 O[2][4];
#pragma unroll
    for (int qs = 0; qs < 2; ++qs)
#pragma unroll
        for (int dt = 0; dt < 4; ++dt) O[qs][dt] = (f32x4){0.f, 0.f, 0.f, 0.f};
    float lsum[2] = {0.f, 0.f};

    const int nch = qt + 1;                          // 64-key chunks
    const f32x4 z4 = {0.f, 0.f, 0.f, 0.f};

    const int lr = lane >> 3;                        // staging sub-row
    const int lc = (lane & 7) ^ lr;                  // pre-swizzled global chunk

#define STAGE(buf, ch)                                                          \
    {                                                                           \
        const int kv0_ = (ch) * 64;                                             \
        _Pragma("unroll")                                                       \
        for (int i_ = 0; i_ < 2; ++i_) {                                        \
            int slot_ = i_ * 4 + w;                                             \
            int r_ = slot_ * 8 + lr;                                            \
            gload16(&Kh[(size_t)(kv0_ + r_) * 64 + lc * 8],                     \
                    &Ks[buf][slot_ * 512 + lane * 8]);                          \
            gload16(&Vh[(size_t)r_ * Tn + kv0_ + lc * 8],                       \
                    &Vs[buf][slot_ * 512 + lane * 8]);                          \
        }                                                                       \
    }

    STAGE(0, 0);
    __syncthreads();

    for (int ch = 0; ch < nch; ++ch) {
        if (ch + 1 < nch) STAGE((ch + 1) & 1, ch + 1);
        const int kv0 = ch * 64;
        const int cur = ch & 1;

        if ((ch & 1) == par && kv0 <= wrow0 + 31) {  // this wave's parity + live
            // ---- S^T = K·Q : 4 key-subtiles x 2 query-subtiles (K frags shared)
            f32x4 sacc[2][4];
#pragma unroll
            for (int sub = 0; sub < 4; ++sub) {
                const int krow = sub * 16 + qi;
                s16x8 ka = *(const s16x8*)&Ks[cur][krow * 64 + ((g ^ (qi & 7))) * 8];
                s16x8 kc = *(const s16x8*)&Ks[cur][krow * 64 + (((4 | g) ^ (qi & 7))) * 8];
#pragma unroll
                for (int qs = 0; qs < 2; ++qs) {
                    f32x4 t0 = __builtin_amdgcn_mfma_f32_16x16x32_bf16(ka, qf[qs][0], z4, 0, 0, 0);
                    sacc[qs][sub] = __builtin_amdgcn_mfma_f32_16x16x32_bf16(kc, qf[qs][1], t0, 0, 0, 0);
                }
            }

            // ---- P = exp2(S), partial l, bf16 fragments ----
            s16x8 pf[2][2];
#pragma unroll
            for (int qs = 0; qs < 2; ++qs) {
                const int qsbase = wrow0 + qs * 16;
                const int qrow = qsbase + qi;
                float pe[16];
                if (kv0 + 63 <= qsbase) {            // interior: no masking
#pragma unroll
                    for (int e2 = 0; e2 < 16; ++e2)
                        pe[e2] = exp2f(sacc[qs][e2 >> 2][e2 & 3]);
                } else {
#pragma unroll
                    for (int sub = 0; sub < 4; ++sub)
#pragma unroll
                        for (int r = 0; r < 4; ++r) {
                            int key = kv0 + sub * 16 + 4 * g + r;
                            pe[sub * 4 + r] = (key <= qrow) ? exp2f(sacc[qs][sub][r]) : 0.f;
                        }
                }
                {   // tree sum into per-lane partial
                    float a0 = (pe[0] + pe[1]) + (pe[2] + pe[3]);
                    float a1 = (pe[4] + pe[5]) + (pe[6] + pe[7]);
                    float a2 = (pe[8] + pe[9]) + (pe[10] + pe[11]);
                    float a3 = (pe[12] + pe[13]) + (pe[14] + pe[15]);
                    lsum[qs] += (a0 + a1) + (a2 + a3);
                }
#pragma unroll
                for (int c = 0; c < 2; ++c)
#pragma unroll
                    for (int e2 = 0; e2 < 8; ++e2) pf[qs][c][e2] = f2bs(pe[c * 8 + e2]);
            }

            // ---- O += P·V (V frags shared across qs) ----
#pragma unroll
            for (int c = 0; c < 2; ++c)
#pragma unroll
                for (int dt = 0; dt < 4; ++dt) {
                    const int vrow = dt * 16 + qi;
                    s16x8 vf = *(const s16x8*)&Vs[cur][vrow * 64 +
                                                       ((((c << 2) | g) ^ (qi & 7))) * 8];
#pragma unroll
                    for (int qs = 0; qs < 2; ++qs)
                        O[qs][dt] = __builtin_amdgcn_mfma_f32_16x16x32_bf16(
                            pf[qs][c], vf, O[qs][dt], 0, 0, 0);
                }
        }
        __syncthreads();
    }
#undef STAGE

    // ---- reduce own l across lane groups ----
    lsum[0] += __shfl_xor(lsum[0], 16); lsum[0] += __shfl_xor(lsum[0], 32);
    lsum[1] += __shfl_xor(lsum[1], 16); lsum[1] += __shfl_xor(lsum[1], 32);

    // ---- parity merge via LDS scratch (fixed base => plain sums) ----
    f32x4* Of4 = (f32x4*)&Ks[0][0];                  // 16 KB: 2 halves x 64 lanes x 8
    float* Lf = (float*)&Vs[0][0];                   // 64 floats
    if (w >= 2) {                                    // odd-parity waves publish
#pragma unroll
        for (int qs = 0; qs < 2; ++qs)
#pragma unroll
            for (int dt = 0; dt < 4; ++dt)
                Of4[(p * 64 + lane) * 8 + ((qs * 4 + dt) ^ (lane & 7))] = O[qs][dt];
        if (g == 0) {
            Lf[p * 32 + qi] = lsum[0];
            Lf[p * 32 + 16 + qi] = lsum[1];
        }
    }
    __syncthreads();
    if (w < 2) {                                     // even-parity waves merge+store
        float lt[2];
        lt[0] = lsum[0] + Lf[p * 32 + qi];
        lt[1] = lsum[1] + Lf[p * 32 + 16 + qi];
#pragma unroll
        for (int qs = 0; qs < 2; ++qs) {
#pragma unroll
            for (int dt = 0; dt < 4; ++dt) {
                f32x4 part = Of4[(p * 64 + lane) * 8 + ((qs * 4 + dt) ^ (lane & 7))];
                O[qs][dt][0] += part[0]; O[qs][dt][1] += part[1];
                O[qs][dt][2] += part[2]; O[qs][dt][3] += part[3];
            }
#pragma unroll
            for (int r = 0; r < 4; ++r) {
                float li = __shfl(lt[qs], 4 * g + r);
                float inv = 1.f / li;
                int t = wrow0 + qs * 16 + 4 * g + r;
#pragma unroll
                for (int dt = 0; dt < 4; ++dt)
                    AO[((size_t)(b * Tn + t)) * Cn + h * 64 + dt * 16 + qi] =
                        f2bs(O[qs][dt][r] * inv);
            }
        }
    }
}

// ---------------- launcher ----------------

extern "C" void kernel_launch(void* const* d_in, const int* in_sizes, int n_in,
                              void* d_out, int out_size, void* d_ws, size_t ws_size,
                              hipStream_t stream) {
    const float* x = (const float*)d_in[0];
    const float* Wqkv = (const float*)d_in[1];
    const float* Wproj = (const float*)d_in[2];
    float* out = (float*)d_out;

    char* ws = (char*)d_ws;
    size_t o = 0;
    short* xb = (short*)(ws + o);      o += (size_t)BT * Cn * 2;            // 8MB (AO alias)
    short* wqkvT = (short*)(ws + o);   o += (size_t)NQKV * Cn * 2;          // 1.5MB
    short* wprojT = (short*)(ws + o);  o += (size_t)Cn * Cn * 2;            // 0.5MB
    short* Qb = (short*)(ws + o);      o += (size_t)Bn * Hn * Tn * Dn * 2;  // 8MB
    short* Kb = (short*)(ws + o);      o += (size_t)Bn * Hn * Tn * Dn * 2;  // 8MB
    short* Vt = (short*)(ws + o);      o += (size_t)Bn * Hn * Tn * Dn * 2;  // 8MB
    float2* csT = (float2*)(ws + o);   o += (size_t)Tn * Dn * 8;            // 1MB

    k_conv_x<<<BT * Cn / 4 / 256, 256, 0, stream>>>(x, xb);
    k_wTt<<<dim3(256), 256, 0, stream>>>(Wqkv, Wproj, wqkvT, wprojT);
    k_rope<<<Tn * Dn / 256, 256, 0, stream>>>(csT);

    gemm_kernel<0><<<dim3(NQKV / 128, BT / 128), 256, 0, stream>>>(
        xb, wqkvT, csT, Qb, Kb, Vt, nullptr);

    attn_kernel<<<dim3(1024), 256, 0, stream>>>(Qb, Kb, Vt, xb /*AO alias*/);

    gemm_kernel<1><<<dim3(Cn / 128, BT / 128), 256, 0, stream>>>(
        xb /*AO*/, wprojT, csT, nullptr, nullptr, nullptr, out);
}

// Round 11
// 117.625 us; speedup vs baseline: 1.0294x; 1.0294x over previous
//
#include <hip/hip_runtime.h>
#include <hip/hip_bf16.h>
#include <stdint.h>

// Problem constants (B=4, T=2048, C=512, H=8, D=64)
constexpr int Bn = 4;
constexpr int Tn = 2048;
constexpr int Cn = 512;
constexpr int Hn = 8;
constexpr int Dn = 64;
constexpr int BT = Bn * Tn;          // 8192
constexpr int NQKV = 3 * Cn;         // 1536

typedef __attribute__((ext_vector_type(4))) float  f32x4;
typedef __attribute__((ext_vector_type(8))) short  s16x8;
typedef __attribute__((ext_vector_type(4))) short  s16x4;

__device__ __forceinline__ short f2bs(float f) {
    __hip_bfloat16 h = __float2bfloat16(f);
    return *reinterpret_cast<short*>(&h);
}

// async global->LDS, 16B per lane (linear LDS dest: wave base + lane*16)
__device__ __forceinline__ void gload16(const short* g, short* l) {
    __builtin_amdgcn_global_load_lds(
        (const __attribute__((address_space(1))) void*)g,
        (__attribute__((address_space(3))) void*)l, 16, 0, 0);
}

// ---------------- conversion / setup kernels ----------------

__global__ __launch_bounds__(256) void k_conv_x(const float* __restrict__ x,
                                                short* __restrict__ xb) {
    int i = blockIdx.x * 256 + threadIdx.x;          // one float4 per thread
    f32x4 v = reinterpret_cast<const f32x4*>(x)[i];
    s16x4 o;
    o[0] = f2bs(v[0]); o[1] = f2bs(v[1]); o[2] = f2bs(v[2]); o[3] = f2bs(v[3]);
    reinterpret_cast<s16x4*>(xb)[i] = o;
}

// Coalesced weight transpose+convert via 64x64 LDS tile (both weights, 1 dispatch).
__global__ __launch_bounds__(256) void k_wTt(const float* __restrict__ Wqkv,
                                             const float* __restrict__ Wproj,
                                             short* __restrict__ wqkvT,
                                             short* __restrict__ wprojT) {
    int bid = blockIdx.x;
    const float* W; short* out; int N, n0, k0;
    if (bid < 192) {                  // 1536/64 * 512/64 = 24*8
        W = Wqkv; out = wqkvT; N = NQKV;
        n0 = (bid >> 3) * 64; k0 = (bid & 7) * 64;
    } else {
        bid -= 192;                   // 512/64 * 512/64 = 8*8
        W = Wproj; out = wprojT; N = Cn;
        n0 = (bid >> 3) * 64; k0 = (bid & 7) * 64;
    }
    __shared__ float lds[64 * 65];
    const int tid = threadIdx.x;
#pragma unroll
    for (int i = 0; i < 16; ++i) {
        int flat = i * 256 + tid;
        int k = flat >> 6, n = flat & 63;
        lds[n * 65 + k] = W[(size_t)(k0 + k) * N + n0 + n];
    }
    __syncthreads();
#pragma unroll
    for (int i = 0; i < 16; ++i) {
        int flat = i * 256 + tid;
        int n = flat >> 6, k = flat & 63;
        out[(size_t)(n0 + n) * 512 + k0 + k] = f2bs(lds[n * 65 + k]);
    }
}

// packed cos/sin table: csT[t*64+d] = (cos, sin)
__global__ __launch_bounds__(256) void k_rope(float2* __restrict__ csT) {
    int i = blockIdx.x * 256 + threadIdx.x;          // < T*D
    int t = i >> 6, d = i & 63;
    float inv = exp2f(-(float)(d & 31) * 0.41524101186f);
    float fr = (float)t * inv;
    csT[i] = make_float2(cosf(fr), sinf(fr));
}

// ---------------- GEMM (128x128 tile, BK=64, double-buffered LDS) -------------
// (unchanged from round 9 — staging hides under the 32-MFMA compute phase)

template <int MODE>
__global__ __launch_bounds__(256, 2) void gemm_kernel(
    const short* __restrict__ A, const short* __restrict__ Bt,
    const float2* __restrict__ csT,
    short* __restrict__ Qb, short* __restrict__ Kb, short* __restrict__ Vt,
    float* __restrict__ outF) {
    const int m0 = blockIdx.y * 128;
    const int n0 = blockIdx.x * 128;
    const int tid = threadIdx.x;
    const int w = tid >> 6, lane = tid & 63;
    const int qi = lane & 15, g = lane >> 4;
    const int wr = w >> 1, wc = w & 1;

    __shared__ short As[2][128 * 64];
    __shared__ short Bs[2][128 * 64];

    f32x4 acc[4][4];
#pragma unroll
    for (int mt = 0; mt < 4; ++mt)
#pragma unroll
        for (int nt = 0; nt < 4; ++nt) acc[mt][nt] = (f32x4){0.f, 0.f, 0.f, 0.f};

    const int lr = lane >> 3;           // sub-row within 8-row slot
    const int lc = (lane & 7) ^ lr;     // pre-swizzled global chunk

#define STAGEG(buf, k0)                                                         \
    {                                                                           \
        _Pragma("unroll")                                                       \
        for (int s4_ = 0; s4_ < 4; ++s4_) {                                     \
            int slot_ = s4_ * 4 + w;                                            \
            int r_ = slot_ * 8 + lr;                                            \
            gload16(&A[(size_t)(m0 + r_) * 512 + (k0) + lc * 8],                \
                    &As[buf][slot_ * 512 + lane * 8]);                          \
            gload16(&Bt[(size_t)(n0 + r_) * 512 + (k0) + lc * 8],               \
                    &Bs[buf][slot_ * 512 + lane * 8]);                          \
        }                                                                       \
    }

    STAGEG(0, 0);
    __syncthreads();

    for (int it = 0; it < 8; ++it) {                 // K = 8 * 64
        if (it + 1 < 8) STAGEG((it + 1) & 1, (it + 1) * 64);
        const int cur = it & 1;
#pragma unroll
        for (int kk = 0; kk < 2; ++kk) {
            s16x8 af[4], bf[4];
#pragma unroll
            for (int mt = 0; mt < 4; ++mt) {
                int row = wr * 64 + mt * 16 + qi;
                af[mt] = *(const s16x8*)&As[cur][row * 64 + (((kk << 2) | g) ^ (qi & 7)) * 8];
            }
#pragma unroll
            for (int nt = 0; nt < 4; ++nt) {
                int row = wc * 64 + nt * 16 + qi;
                bf[nt] = *(const s16x8*)&Bs[cur][row * 64 + (((kk << 2) | g) ^ (qi & 7)) * 8];
            }
#pragma unroll
            for (int mt = 0; mt < 4; ++mt)
#pragma unroll
                for (int nt = 0; nt < 4; ++nt)
                    acc[mt][nt] = __builtin_amdgcn_mfma_f32_16x16x32_bf16(
                        af[mt], bf[nt], acc[mt][nt], 0, 0, 0);
        }
        __syncthreads();
    }
#undef STAGEG

    if (MODE == 1) {
#pragma unroll
        for (int mt = 0; mt < 4; ++mt)
#pragma unroll
            for (int nt = 0; nt < 4; ++nt)
#pragma unroll
                for (int r = 0; r < 4; ++r)
                    outF[(size_t)(m0 + wr * 64 + mt * 16 + 4 * g + r) * 512 +
                         n0 + wc * 64 + nt * 16 + qi] = acc[mt][nt][r];
    } else {
        const int seg64 = (n0 >> 6) + wc;            // = h*3 + seg
        const int h = seg64 / 3;
        const int seg = seg64 % 3;                   // 0=q 1=k 2=v
        const int b = m0 >> 11;
        const int tb = (m0 & 2047) + wr * 64;
        const float QSC = 0.125f * 1.44269504f;      // pre-fold softmax scale into Q
        if (seg == 2) {
            // V transposed + fragment-permuted: Vt[bh][d][ (t&~31) + g2*8 + sub2*4 + r2 ]
            const size_t vbase = (size_t)(b * Hn + h) * Dn;
#pragma unroll
            for (int mt = 0; mt < 4; ++mt)
#pragma unroll
                for (int nt = 0; nt < 4; ++nt)
#pragma unroll
                    for (int r = 0; r < 4; ++r) {
                        int t = tb + mt * 16 + 4 * g + r;
                        int d = nt * 16 + qi;
                        int o = t & 31;
                        int jj = (t & ~31) + ((o >> 2) & 3) * 8 + (o >> 4) * 4 + (o & 3);
                        Vt[(vbase + d) * Tn + jj] = f2bs(acc[mt][nt][r]);
                    }
        } else {
            short* dst = (seg == 0) ? Qb : Kb;
            const float post = (seg == 0) ? QSC : 1.0f;
            const size_t headbase = (size_t)(b * Hn + h) * Tn;
#pragma unroll
            for (int mt = 0; mt < 4; ++mt)
#pragma unroll
                for (int nt = 0; nt < 4; ++nt)
#pragma unroll
                    for (int r = 0; r < 4; ++r) {
                        int t = tb + mt * 16 + 4 * g + r;
                        int d = nt * 16 + qi;
                        float val = acc[mt][nt][r];
                        float pv = (nt < 2) ? -acc[mt][nt + 2][r] : acc[mt][nt - 2][r];
                        float2 cs = csT[t * 64 + d];
                        dst[(headbase + t) * Dn + d] = f2bs((val * cs.x + pv * cs.y) * post);
                    }
        }
    }
}

// ---------------- causal flash attention (thin 2-wave blocks, 32 q-rows/wave) --
// Block = 2 waves (128 thr), 64 q-rows of one bh; wave w owns rows q0+w*32..+31
// and computes EVERY chunk for its own rows (no idle waves, no merge).
// K/V fragments are reused across each wave's 2 q-subtiles -> LDS read traffic
// per chunk-visit = 2 x 16KB = 32KB (HALF of round 9). SINGLE-buffer LDS (16KB)
// -> up to 10 blocks/CU (20 waves, 5/SIMD); stage latency is covered by
// cross-block TLP instead of a double buffer. Grid 1024 (32 qt x 32 bh),
// heavy-first, bh in low bits. FIXED-BASE softmax (Q pre-scaled): P = exp2(S).
// Per chunk: STAGE -> barrier(+vmcnt drain) -> compute -> barrier.

__global__ __launch_bounds__(128, 4) void attn_kernel(const short* __restrict__ Qb,
                                                      const short* __restrict__ Kb,
                                                      const short* __restrict__ Vt,
                                                      short* __restrict__ AO) {
    const int idx = blockIdx.x;
    const int bh = idx & 31;
    const int qt = 31 - (idx >> 5);                  // heavy tiles dispatch first
    const int q0 = qt * 64;
    const int tid = threadIdx.x;
    const int w = tid >> 6, lane = tid & 63;
    const int qi = lane & 15, g = lane >> 4;
    const int b = bh >> 3, h = bh & 7;

    __shared__ short Ks[64 * 64];        // [key][d], chunk-swizzled (8KB)
    __shared__ short Vs[64 * 64];        // [d][key-perm], chunk-swizzled (8KB)

    const short* Qh = Qb + (size_t)bh * Tn * Dn;
    const short* Kh = Kb + (size_t)bh * Tn * Dn;
    const short* Vh = Vt + (size_t)bh * Dn * Tn;

    const int wrow0 = q0 + w * 32;       // wave's 32 query rows
    s16x8 qf[2][2];
#pragma unroll
    for (int qs = 0; qs < 2; ++qs)
#pragma unroll
        for (int dh = 0; dh < 2; ++dh)
            qf[qs][dh] = *(const s16x8*)&Qh[(size_t)(wrow0 + qs * 16 + qi) * Dn +
                                            dh * 32 + g * 8];

    f32x4 O[2][4];
#pragma unroll
    for (int qs = 0; qs < 2; ++qs)
#pragma unroll
        for (int dt = 0; dt < 4; ++dt) O[qs][dt] = (f32x4){0.f, 0.f, 0.f, 0.f};
    float lsum[2] = {0.f, 0.f};

    const int nch = qt + 1;                          // 64-key chunks
    const f32x4 z4 = {0.f, 0.f, 0.f, 0.f};

    const int lr = lane >> 3;                        // staging sub-row
    const int lc = (lane & 7) ^ lr;                  // pre-swizzled global chunk

    for (int ch = 0; ch < nch; ++ch) {
        const int kv0 = ch * 64;
        // ---- stage K(8KB)+V(8KB): 8 slots of 8 rows, slot = i*2+w ----
#pragma unroll
        for (int i_ = 0; i_ < 4; ++i_) {
            int slot_ = i_ * 2 + w;
            int r_ = slot_ * 8 + lr;
            gload16(&Kh[(size_t)(kv0 + r_) * 64 + lc * 8],
                    &Ks[slot_ * 512 + lane * 8]);
            gload16(&Vh[(size_t)r_ * Tn + kv0 + lc * 8],
                    &Vs[slot_ * 512 + lane * 8]);
        }
        __syncthreads();                             // drains vmcnt -> LDS ready

        // ---- S^T = K·Q : 4 key-subtiles x 2 q-subtiles (K frags shared) ----
        f32x4 sacc[2][4];
#pragma unroll
        for (int sub = 0; sub < 4; ++sub) {
            const int krow = sub * 16 + qi;
            s16x8 ka = *(const s16x8*)&Ks[krow * 64 + ((g ^ (qi & 7))) * 8];
            s16x8 kc = *(const s16x8*)&Ks[krow * 64 + (((4 | g) ^ (qi & 7))) * 8];
#pragma unroll
            for (int qs = 0; qs < 2; ++qs) {
                f32x4 t0 = __builtin_amdgcn_mfma_f32_16x16x32_bf16(ka, qf[qs][0], z4, 0, 0, 0);
                sacc[qs][sub] = __builtin_amdgcn_mfma_f32_16x16x32_bf16(kc, qf[qs][1], t0, 0, 0, 0);
            }
        }

        // ---- P = exp2(S), partial l, bf16 fragments ----
        s16x8 pf[2][2];
#pragma unroll
        for (int qs = 0; qs < 2; ++qs) {
            const int qsbase = wrow0 + qs * 16;
            const int qrow = qsbase + qi;
            float pe[16];
            if (kv0 + 63 <= qsbase) {                // interior: no masking
#pragma unroll
                for (int e2 = 0; e2 < 16; ++e2)
                    pe[e2] = exp2f(sacc[qs][e2 >> 2][e2 & 3]);
            } else {
#pragma unroll
                for (int sub = 0; sub < 4; ++sub)
#pragma unroll
                    for (int r = 0; r < 4; ++r) {
                        int key = kv0 + sub * 16 + 4 * g + r;
                        pe[sub * 4 + r] = (key <= qrow) ? exp2f(sacc[qs][sub][r]) : 0.f;
                    }
            }
            {   // tree sum into per-lane partial
                float a0 = (pe[0] + pe[1]) + (pe[2] + pe[3]);
                float a1 = (pe[4] + pe[5]) + (pe[6] + pe[7]);
                float a2 = (pe[8] + pe[9]) + (pe[10] + pe[11]);
                float a3 = (pe[12] + pe[13]) + (pe[14] + pe[15]);
                lsum[qs] += (a0 + a1) + (a2 + a3);
            }
#pragma unroll
            for (int c = 0; c < 2; ++c)
#pragma unroll
                for (int e2 = 0; e2 < 8; ++e2) pf[qs][c][e2] = f2bs(pe[c * 8 + e2]);
        }

        // ---- O += P·V (V frags shared across qs) ----
#pragma unroll
        for (int c = 0; c < 2; ++c)
#pragma unroll
            for (int dt = 0; dt < 4; ++dt) {
                const int vrow = dt * 16 + qi;
                s16x8 vf = *(const s16x8*)&Vs[vrow * 64 +
                                              ((((c << 2) | g) ^ (qi & 7))) * 8];
#pragma unroll
                for (int qs = 0; qs < 2; ++qs)
                    O[qs][dt] = __builtin_amdgcn_mfma_f32_16x16x32_bf16(
                        pf[qs][c], vf, O[qs][dt], 0, 0, 0);
            }
        __syncthreads();                             // protect buffer for next stage
    }

    // ---- cross-lane l reduce + normalize + direct store (wave owns its rows) --
    lsum[0] += __shfl_xor(lsum[0], 16); lsum[0] += __shfl_xor(lsum[0], 32);
    lsum[1] += __shfl_xor(lsum[1], 16); lsum[1] += __shfl_xor(lsum[1], 32);

#pragma unroll
    for (int qs = 0; qs < 2; ++qs) {
#pragma unroll
        for (int r = 0; r < 4; ++r) {
            float li = __shfl(lsum[qs], 4 * g + r);
            float inv = 1.f / li;
            int t = wrow0 + qs * 16 + 4 * g + r;
#pragma unroll
            for (int dt = 0; dt < 4; ++dt)
                AO[((size_t)(b * Tn + t)) * Cn + h * 64 + dt * 16 + qi] =
                    f2bs(O[qs][dt][r] * inv);
        }
    }
}

// ---------------- launcher ----------------

extern "C" void kernel_launch(void* const* d_in, const int* in_sizes, int n_in,
                              void* d_out, int out_size, void* d_ws, size_t ws_size,
                              hipStream_t stream) {
    const float* x = (const float*)d_in[0];
    const float* Wqkv = (const float*)d_in[1];
    const float* Wproj = (const float*)d_in[2];
    float* out = (float*)d_out;

    char* ws = (char*)d_ws;
    size_t o = 0;
    short* xb = (short*)(ws + o);      o += (size_t)BT * Cn * 2;            // 8MB (AO alias)
    short* wqkvT = (short*)(ws + o);   o += (size_t)NQKV * Cn * 2;          // 1.5MB
    short* wprojT = (short*)(ws + o);  o += (size_t)Cn * Cn * 2;            // 0.5MB
    short* Qb = (short*)(ws + o);      o += (size_t)Bn * Hn * Tn * Dn * 2;  // 8MB
    short* Kb = (short*)(ws + o);      o += (size_t)Bn * Hn * Tn * Dn * 2;  // 8MB
    short* Vt = (short*)(ws + o);      o += (size_t)Bn * Hn * Tn * Dn * 2;  // 8MB
    float2* csT = (float2*)(ws + o);   o += (size_t)Tn * Dn * 8;            // 1MB

    k_conv_x<<<BT * Cn / 4 / 256, 256, 0, stream>>>(x, xb);
    k_wTt<<<dim3(256), 256, 0, stream>>>(Wqkv, Wproj, wqkvT, wprojT);
    k_rope<<<Tn * Dn / 256, 256, 0, stream>>>(csT);

    gemm_kernel<0><<<dim3(NQKV / 128, BT / 128), 256, 0, stream>>>(
        xb, wqkvT, csT, Qb, Kb, Vt, nullptr);

    attn_kernel<<<dim3(1024), 128, 0, stream>>>(Qb, Kb, Vt, xb /*AO alias*/);

    gemm_kernel<1><<<dim3(Cn / 128, BT / 128), 256, 0, stream>>>(
        xb /*AO*/, wprojT, csT, nullptr, nullptr, nullptr, out);
}

// Round 12
// 95.930 us; speedup vs baseline: 1.2622x; 1.2262x over previous
//
#include <hip/hip_runtime.h>
#include <hip/hip_bf16.h>
#include <stdint.h>

// Problem constants (B=4, T=2048, C=512, H=8, D=64)
constexpr int Bn = 4;
constexpr int Tn = 2048;
constexpr int Cn = 512;
constexpr int Hn = 8;
constexpr int Dn = 64;
constexpr int BT = Bn * Tn;          // 8192
constexpr int NQKV = 3 * Cn;         // 1536

typedef __attribute__((ext_vector_type(4))) float  f32x4;
typedef __attribute__((ext_vector_type(8))) short  s16x8;
typedef __attribute__((ext_vector_type(4))) short  s16x4;

__device__ __forceinline__ short f2bs(float f) {
    __hip_bfloat16 h = __float2bfloat16(f);
    return *reinterpret_cast<short*>(&h);
}

// async global->LDS, 16B per lane (linear LDS dest: wave base + lane*16)
__device__ __forceinline__ void gload16(const short* g, short* l) {
    __builtin_amdgcn_global_load_lds(
        (const __attribute__((address_space(1))) void*)g,
        (__attribute__((address_space(3))) void*)l, 16, 0, 0);
}

// Unit table: 48 entries/bh, heavy-first. entry = (qt<<16)|(chlo<<8)|chhi.
// qt 0..15 unsplit; qt 16..31 split into [0,(qt+1)/2) and [(qt+1)/2, qt+1).
__device__ const uint32_t UT[48] = {
    (31u<<16)|(0u<<8)|16u, (31u<<16)|(16u<<8)|32u, (30u<<16)|(15u<<8)|31u, (15u<<16)|(0u<<8)|16u,
    (30u<<16)|(0u<<8)|15u, (29u<<16)|(0u<<8)|15u, (29u<<16)|(15u<<8)|30u, (28u<<16)|(14u<<8)|29u, (14u<<16)|(0u<<8)|15u,
    (28u<<16)|(0u<<8)|14u, (27u<<16)|(0u<<8)|14u, (27u<<16)|(14u<<8)|28u, (26u<<16)|(13u<<8)|27u, (13u<<16)|(0u<<8)|14u,
    (26u<<16)|(0u<<8)|13u, (25u<<16)|(0u<<8)|13u, (25u<<16)|(13u<<8)|26u, (24u<<16)|(12u<<8)|25u, (12u<<16)|(0u<<8)|13u,
    (24u<<16)|(0u<<8)|12u, (23u<<16)|(0u<<8)|12u, (23u<<16)|(12u<<8)|24u, (22u<<16)|(11u<<8)|23u, (11u<<16)|(0u<<8)|12u,
    (22u<<16)|(0u<<8)|11u, (21u<<16)|(0u<<8)|11u, (21u<<16)|(11u<<8)|22u, (20u<<16)|(10u<<8)|21u, (10u<<16)|(0u<<8)|11u,
    (20u<<16)|(0u<<8)|10u, (19u<<16)|(0u<<8)|10u, (19u<<16)|(10u<<8)|20u, (18u<<16)|(9u<<8)|19u,  (9u<<16)|(0u<<8)|10u,
    (18u<<16)|(0u<<8)|9u,  (17u<<16)|(0u<<8)|9u,  (17u<<16)|(9u<<8)|18u,  (16u<<16)|(8u<<8)|17u,  (8u<<16)|(0u<<8)|9u,
    (16u<<16)|(0u<<8)|8u,  (7u<<16)|(0u<<8)|8u,
    (6u<<16)|(0u<<8)|7u, (5u<<16)|(0u<<8)|6u, (4u<<16)|(0u<<8)|5u, (3u<<16)|(0u<<8)|4u,
    (2u<<16)|(0u<<8)|3u, (1u<<16)|(0u<<8)|2u, (0u<<16)|(0u<<8)|1u
};

// ---------------- conversion / setup kernels ----------------

__global__ __launch_bounds__(256) void k_conv_x(const float* __restrict__ x,
                                                short* __restrict__ xb) {
    int i = blockIdx.x * 256 + threadIdx.x;          // one float4 per thread
    f32x4 v = reinterpret_cast<const f32x4*>(x)[i];
    s16x4 o;
    o[0] = f2bs(v[0]); o[1] = f2bs(v[1]); o[2] = f2bs(v[2]); o[3] = f2bs(v[3]);
    reinterpret_cast<s16x4*>(xb)[i] = o;
}

// Coalesced weight transpose+convert via 64x64 LDS tile (both weights, 1 dispatch).
__global__ __launch_bounds__(256) void k_wTt(const float* __restrict__ Wqkv,
                                             const float* __restrict__ Wproj,
                                             short* __restrict__ wqkvT,
                                             short* __restrict__ wprojT) {
    int bid = blockIdx.x;
    const float* W; short* out; int N, n0, k0;
    if (bid < 192) {                  // 1536/64 * 512/64 = 24*8
        W = Wqkv; out = wqkvT; N = NQKV;
        n0 = (bid >> 3) * 64; k0 = (bid & 7) * 64;
    } else {
        bid -= 192;                   // 512/64 * 512/64 = 8*8
        W = Wproj; out = wprojT; N = Cn;
        n0 = (bid >> 3) * 64; k0 = (bid & 7) * 64;
    }
    __shared__ float lds[64 * 65];
    const int tid = threadIdx.x;
#pragma unroll
    for (int i = 0; i < 16; ++i) {
        int flat = i * 256 + tid;
        int k = flat >> 6, n = flat & 63;
        lds[n * 65 + k] = W[(size_t)(k0 + k) * N + n0 + n];
    }
    __syncthreads();
#pragma unroll
    for (int i = 0; i < 16; ++i) {
        int flat = i * 256 + tid;
        int n = flat >> 6, k = flat & 63;
        out[(size_t)(n0 + n) * 512 + k0 + k] = f2bs(lds[n * 65 + k]);
    }
}

// packed cos/sin table: csT[t*64+d] = (cos, sin)
__global__ __launch_bounds__(256) void k_rope(float2* __restrict__ csT) {
    int i = blockIdx.x * 256 + threadIdx.x;          // < T*D
    int t = i >> 6, d = i & 63;
    float inv = exp2f(-(float)(d & 31) * 0.41524101186f);
    float fr = (float)t * inv;
    csT[i] = make_float2(cosf(fr), sinf(fr));
}

// ---------------- GEMM (128x128 tile, BK=64, double-buffered LDS) -------------
// (unchanged — staging hides under the 32-MFMA compute phase)

template <int MODE>
__global__ __launch_bounds__(256, 2) void gemm_kernel(
    const short* __restrict__ A, const short* __restrict__ Bt,
    const float2* __restrict__ csT,
    short* __restrict__ Qb, short* __restrict__ Kb, short* __restrict__ Vt,
    float* __restrict__ outF) {
    const int m0 = blockIdx.y * 128;
    const int n0 = blockIdx.x * 128;
    const int tid = threadIdx.x;
    const int w = tid >> 6, lane = tid & 63;
    const int qi = lane & 15, g = lane >> 4;
    const int wr = w >> 1, wc = w & 1;

    __shared__ short As[2][128 * 64];
    __shared__ short Bs[2][128 * 64];

    f32x4 acc[4][4];
#pragma unroll
    for (int mt = 0; mt < 4; ++mt)
#pragma unroll
        for (int nt = 0; nt < 4; ++nt) acc[mt][nt] = (f32x4){0.f, 0.f, 0.f, 0.f};

    const int lr = lane >> 3;           // sub-row within 8-row slot
    const int lc = (lane & 7) ^ lr;     // pre-swizzled global chunk

#define STAGEG(buf, k0)                                                         \
    {                                                                           \
        _Pragma("unroll")                                                       \
        for (int s4_ = 0; s4_ < 4; ++s4_) {                                     \
            int slot_ = s4_ * 4 + w;                                            \
            int r_ = slot_ * 8 + lr;                                            \
            gload16(&A[(size_t)(m0 + r_) * 512 + (k0) + lc * 8],                \
                    &As[buf][slot_ * 512 + lane * 8]);                          \
            gload16(&Bt[(size_t)(n0 + r_) * 512 + (k0) + lc * 8],               \
                    &Bs[buf][slot_ * 512 + lane * 8]);                          \
        }                                                                       \
    }

    STAGEG(0, 0);
    __syncthreads();

    for (int it = 0; it < 8; ++it) {                 // K = 8 * 64
        if (it + 1 < 8) STAGEG((it + 1) & 1, (it + 1) * 64);
        const int cur = it & 1;
#pragma unroll
        for (int kk = 0; kk < 2; ++kk) {
            s16x8 af[4], bf[4];
#pragma unroll
            for (int mt = 0; mt < 4; ++mt) {
                int row = wr * 64 + mt * 16 + qi;
                af[mt] = *(const s16x8*)&As[cur][row * 64 + (((kk << 2) | g) ^ (qi & 7)) * 8];
            }
#pragma unroll
            for (int nt = 0; nt < 4; ++nt) {
                int row = wc * 64 + nt * 16 + qi;
                bf[nt] = *(const s16x8*)&Bs[cur][row * 64 + (((kk << 2) | g) ^ (qi & 7)) * 8];
            }
#pragma unroll
            for (int mt = 0; mt < 4; ++mt)
#pragma unroll
                for (int nt = 0; nt < 4; ++nt)
                    acc[mt][nt] = __builtin_amdgcn_mfma_f32_16x16x32_bf16(
                        af[mt], bf[nt], acc[mt][nt], 0, 0, 0);
        }
        __syncthreads();
    }
#undef STAGEG

    if (MODE == 1) {
#pragma unroll
        for (int mt = 0; mt < 4; ++mt)
#pragma unroll
            for (int nt = 0; nt < 4; ++nt)
#pragma unroll
                for (int r = 0; r < 4; ++r)
                    outF[(size_t)(m0 + wr * 64 + mt * 16 + 4 * g + r) * 512 +
                         n0 + wc * 64 + nt * 16 + qi] = acc[mt][nt][r];
    } else {
        const int seg64 = (n0 >> 6) + wc;            // = h*3 + seg
        const int h = seg64 / 3;
        const int seg = seg64 % 3;                   // 0=q 1=k 2=v
        const int b = m0 >> 11;
        const int tb = (m0 & 2047) + wr * 64;
        const float QSC = 0.125f * 1.44269504f;      // pre-fold softmax scale into Q
        if (seg == 2) {
            // V transposed + fragment-permuted: Vt[bh][d][ (t&~31) + g2*8 + sub2*4 + r2 ]
            const size_t vbase = (size_t)(b * Hn + h) * Dn;
#pragma unroll
            for (int mt = 0; mt < 4; ++mt)
#pragma unroll
                for (int nt = 0; nt < 4; ++nt)
#pragma unroll
                    for (int r = 0; r < 4; ++r) {
                        int t = tb + mt * 16 + 4 * g + r;
                        int d = nt * 16 + qi;
                        int o = t & 31;
                        int jj = (t & ~31) + ((o >> 2) & 3) * 8 + (o >> 4) * 4 + (o & 3);
                        Vt[(vbase + d) * Tn + jj] = f2bs(acc[mt][nt][r]);
                    }
        } else {
            short* dst = (seg == 0) ? Qb : Kb;
            const float post = (seg == 0) ? QSC : 1.0f;
            const size_t headbase = (size_t)(b * Hn + h) * Tn;
#pragma unroll
            for (int mt = 0; mt < 4; ++mt)
#pragma unroll
                for (int nt = 0; nt < 4; ++nt)
#pragma unroll
                    for (int r = 0; r < 4; ++r) {
                        int t = tb + mt * 16 + 4 * g + r;
                        int d = nt * 16 + qi;
                        float val = acc[mt][nt][r];
                        float pv = (nt < 2) ? -acc[mt][nt + 2][r] : acc[mt][nt - 2][r];
                        float2 cs = csT[t * 64 + d];
                        dst[(headbase + t) * Dn + d] = f2bs((val * cs.x + pv * cs.y) * post);
                    }
        }
    }
}

// ---------------- causal flash attention (r9 structure + heavy-tile split-K) ---
// Block = 4 waves (256 thr), 64 q-rows; wave w owns rows q0+w*16..+15.
// Unit table: qt 0..15 unsplit; qt 16..31 split into 2 key-range halves ->
// max 16 chunks per block (critical path halved vs r9's 32). Grid 1536 =
// 48 units x 32 bh (bh low bits), heavy-first; 32KB LDS -> 5 blocks/CU + real
// backfill. Per chunk: stage K+permuted-V into LDS[2] (pre-swizzled source,
// XOR read-back), stage ch+1 BEFORE compute ch. FIXED-BASE softmax (Q
// pre-scaled): P = exp2(S); split halves emit fp32 partial O/l (plain sums).

__global__ __launch_bounds__(256, 4) void attn_kernel(const short* __restrict__ Qb,
                                                      const short* __restrict__ Kb,
                                                      const short* __restrict__ Vt,
                                                      short* __restrict__ AO,
                                                      float* __restrict__ Opart,
                                                      float* __restrict__ Lpart) {
    const int idx = blockIdx.x;
    const int bh = idx & 31;
    const uint32_t e = UT[idx >> 5];
    const int qt = e >> 16;
    const int chlo = (e >> 8) & 255, chhi = e & 255;
    const int q0 = qt * 64;
    const int tid = threadIdx.x;
    const int w = tid >> 6, lane = tid & 63;
    const int qi = lane & 15, g = lane >> 4;
    const int b = bh >> 3, h = bh & 7;

    __shared__ short Ks[2][64 * 64];     // [key][d], chunk-swizzled
    __shared__ short Vs[2][64 * 64];     // [d][key-perm], chunk-swizzled

    const short* Qh = Qb + (size_t)bh * Tn * Dn;
    const short* Kh = Kb + (size_t)bh * Tn * Dn;
    const short* Vh = Vt + (size_t)bh * Dn * Tn;

    const int wrow0 = q0 + w * 16;       // wave's 16 query rows
    s16x8 qf[2];
#pragma unroll
    for (int dh = 0; dh < 2; ++dh)
        qf[dh] = *(const s16x8*)&Qh[(size_t)(wrow0 + qi) * Dn + dh * 32 + g * 8];

    f32x4 O[4];
#pragma unroll
    for (int dt = 0; dt < 4; ++dt) O[dt] = (f32x4){0.f, 0.f, 0.f, 0.f};
    float lsum = 0.f;

    const f32x4 z4 = {0.f, 0.f, 0.f, 0.f};

    const int lr = lane >> 3;                        // staging sub-row
    const int lc = (lane & 7) ^ lr;                  // pre-swizzled global chunk

#define STAGE(buf, ch)                                                          \
    {                                                                           \
        const int kv0_ = (ch) * 64;                                             \
        _Pragma("unroll")                                                       \
        for (int i_ = 0; i_ < 2; ++i_) {                                        \
            int slot_ = i_ * 4 + w;                                             \
            int r_ = slot_ * 8 + lr;                                            \
            gload16(&Kh[(size_t)(kv0_ + r_) * 64 + lc * 8],                     \
                    &Ks[buf][slot_ * 512 + lane * 8]);                          \
            gload16(&Vh[(size_t)r_ * Tn + kv0_ + lc * 8],                       \
                    &Vs[buf][slot_ * 512 + lane * 8]);                          \
        }                                                                       \
    }

    STAGE(0, chlo);
    __syncthreads();

    for (int ch = chlo; ch < chhi; ++ch) {
        const int rel = ch - chlo;
        if (ch + 1 < chhi) STAGE((rel + 1) & 1, ch + 1);
        const int kv0 = ch * 64;
        const int cur = rel & 1;

        if (kv0 <= wrow0 + 15) {                     // wave has live keys here
            // ---- S^T = K·Q : 4 key-subtiles ----
            f32x4 sacc[4];
#pragma unroll
            for (int sub = 0; sub < 4; ++sub) {
                const int krow = sub * 16 + qi;
                s16x8 ka = *(const s16x8*)&Ks[cur][krow * 64 + ((g ^ (qi & 7))) * 8];
                s16x8 kc = *(const s16x8*)&Ks[cur][krow * 64 + (((4 | g) ^ (qi & 7))) * 8];
                f32x4 t0 = __builtin_amdgcn_mfma_f32_16x16x32_bf16(ka, qf[0], z4, 0, 0, 0);
                sacc[sub] = __builtin_amdgcn_mfma_f32_16x16x32_bf16(kc, qf[1], t0, 0, 0, 0);
            }

            // ---- P = exp2(S) (Q pre-scaled), partial l, bf16 fragments ----
            float pe[16];
            if (kv0 + 63 <= wrow0) {                 // interior: no masking
#pragma unroll
                for (int e2 = 0; e2 < 16; ++e2)
                    pe[e2] = exp2f(sacc[e2 >> 2][e2 & 3]);
            } else {
                const int qrow = wrow0 + qi;
#pragma unroll
                for (int sub = 0; sub < 4; ++sub)
#pragma unroll
                    for (int r = 0; r < 4; ++r) {
                        int key = kv0 + sub * 16 + 4 * g + r;
                        pe[sub * 4 + r] = (key <= qrow) ? exp2f(sacc[sub][r]) : 0.f;
                    }
            }
            {   // tree sum into per-lane partial
                float a0 = (pe[0] + pe[1]) + (pe[2] + pe[3]);
                float a1 = (pe[4] + pe[5]) + (pe[6] + pe[7]);
                float a2 = (pe[8] + pe[9]) + (pe[10] + pe[11]);
                float a3 = (pe[12] + pe[13]) + (pe[14] + pe[15]);
                lsum += (a0 + a1) + (a2 + a3);
            }
            s16x8 pf[2];
#pragma unroll
            for (int c = 0; c < 2; ++c)
#pragma unroll
                for (int e2 = 0; e2 < 8; ++e2) pf[c][e2] = f2bs(pe[c * 8 + e2]);

            // ---- O += P·V ----
#pragma unroll
            for (int c = 0; c < 2; ++c)
#pragma unroll
                for (int dt = 0; dt < 4; ++dt) {
                    const int vrow = dt * 16 + qi;
                    s16x8 vf = *(const s16x8*)&Vs[cur][vrow * 64 +
                                                       ((((c << 2) | g) ^ (qi & 7))) * 8];
                    O[dt] = __builtin_amdgcn_mfma_f32_16x16x32_bf16(
                        pf[c], vf, O[dt], 0, 0, 0);
                }
        }
        __syncthreads();
    }
#undef STAGE

    // ---- cross-lane l reduce ----
    lsum += __shfl_xor(lsum, 16);
    lsum += __shfl_xor(lsum, 32);

    if (qt < 16) {
        // ---- direct: normalize + store ----
#pragma unroll
        for (int r = 0; r < 4; ++r) {
            float li = __shfl(lsum, 4 * g + r);
            float inv = 1.f / li;
            int t = wrow0 + 4 * g + r;
#pragma unroll
            for (int dt = 0; dt < 4; ++dt)
                AO[((size_t)(b * Tn + t)) * Cn + h * 64 + dt * 16 + qi] =
                    f2bs(O[dt][r] * inv);
        }
    } else {
        // ---- split half: emit fp32 partials (fixed base => plain sums) ----
        const int pu = (bh * 16 + (qt - 16)) * 2 + (chlo ? 1 : 0);
        float* Op = Opart + (size_t)pu * 4096;
        if (g == 0) Lpart[pu * 64 + w * 16 + qi] = lsum;
#pragma unroll
        for (int r = 0; r < 4; ++r) {
            int lrow = w * 16 + 4 * g + r;
#pragma unroll
            for (int dt = 0; dt < 4; ++dt)
                Op[lrow * 64 + dt * 16 + qi] = O[dt][r];
        }
    }
}

// ---------------- split-K combine (fixed base: plain sums) ----------------
// 512 blocks = 32 bh x 16 split q-tiles; thread -> (row, 16-wide d group).

__global__ __launch_bounds__(256) void combine_kernel(const float* __restrict__ Opart,
                                                      const float* __restrict__ Lpart,
                                                      short* __restrict__ AO) {
    const int u = blockIdx.x;
    const int bh = u & 31, sqt = u >> 5;
    const int pu = (bh * 16 + sqt) * 2;
    const int row = threadIdx.x >> 2;
    const int d0 = (threadIdx.x & 3) * 16;

    const float* O0 = Opart + (size_t)pu * 4096 + row * 64 + d0;
    const float* O1 = O0 + 4096;
    float l = Lpart[pu * 64 + row] + Lpart[(pu + 1) * 64 + row];
    float inv = 1.f / l;

    const int b = bh >> 3, h = bh & 7;
    const int t = (16 + sqt) * 64 + row;
    short* dst = &AO[((size_t)(b * Tn + t)) * Cn + h * 64 + d0];

    s16x8 ov;
#pragma unroll
    for (int j = 0; j < 8; ++j) ov[j] = f2bs((O0[j] + O1[j]) * inv);
    *(s16x8*)dst = ov;
#pragma unroll
    for (int j = 0; j < 8; ++j) ov[j] = f2bs((O0[8 + j] + O1[8 + j]) * inv);
    *(s16x8*)(dst + 8) = ov;
}

// ---------------- launcher ----------------

extern "C" void kernel_launch(void* const* d_in, const int* in_sizes, int n_in,
                              void* d_out, int out_size, void* d_ws, size_t ws_size,
                              hipStream_t stream) {
    const float* x = (const float*)d_in[0];
    const float* Wqkv = (const float*)d_in[1];
    const float* Wproj = (const float*)d_in[2];
    float* out = (float*)d_out;

    char* ws = (char*)d_ws;
    size_t o = 0;
    short* xb = (short*)(ws + o);      o += (size_t)BT * Cn * 2;            // 8MB (AO alias)
    short* wqkvT = (short*)(ws + o);   o += (size_t)NQKV * Cn * 2;          // 1.5MB
    short* wprojT = (short*)(ws + o);  o += (size_t)Cn * Cn * 2;            // 0.5MB
    short* Qb = (short*)(ws + o);      o += (size_t)Bn * Hn * Tn * Dn * 2;  // 8MB
    short* Kb = (short*)(ws + o);      o += (size_t)Bn * Hn * Tn * Dn * 2;  // 8MB
    short* Vt = (short*)(ws + o);      o += (size_t)Bn * Hn * Tn * Dn * 2;  // 8MB
    float2* csT = (float2*)(ws + o);   o += (size_t)Tn * Dn * 8;            // 1MB
    float* Opart = (float*)(ws + o);   o += (size_t)512 * 2 * 4096 * 4;     // 16.8MB
    float* Lpart = (float*)(ws + o);   o += (size_t)512 * 2 * 64 * 4;       // 256KB

    k_conv_x<<<BT * Cn / 4 / 256, 256, 0, stream>>>(x, xb);
    k_wTt<<<dim3(256), 256, 0, stream>>>(Wqkv, Wproj, wqkvT, wprojT);
    k_rope<<<Tn * Dn / 256, 256, 0, stream>>>(csT);

    gemm_kernel<0><<<dim3(NQKV / 128, BT / 128), 256, 0, stream>>>(
        xb, wqkvT, csT, Qb, Kb, Vt, nullptr);

    attn_kernel<<<dim3(48 * 32), 256, 0, stream>>>(Qb, Kb, Vt, xb /*AO alias*/,
                                                   Opart, Lpart);

    combine_kernel<<<dim3(512), 256, 0, stream>>>(Opart, Lpart, xb /*AO alias*/);

    gemm_kernel<1><<<dim3(Cn / 128, BT / 128), 256, 0, stream>>>(
        xb /*AO*/, wprojT, csT, nullptr, nullptr, nullptr, out);
}